// Round 8
// baseline (318.663 us; speedup 1.0000x reference)
//
#include <hip/hip_runtime.h>
#include <stdint.h>

#define IN_F 4096
#define OUT_F 4096
#define NTRI 2016

typedef unsigned short u16;
typedef __attribute__((ext_vector_type(8))) short short8;
typedef __attribute__((ext_vector_type(4))) float f32x4;
typedef __attribute__((ext_vector_type(4))) int i32x4;
typedef __attribute__((ext_vector_type(4))) unsigned short u16x4;

__device__ __forceinline__ u16 f2bf(float f) {
    uint32_t u = __builtin_bit_cast(uint32_t, f);
    u = (u + 0x7FFFu + ((u >> 16) & 1u)) >> 16;   // round-to-nearest-even
    return (u16)u;
}

__device__ __forceinline__ void gload16(const void* g, void* l) {
    __builtin_amdgcn_global_load_lds((__attribute__((address_space(1))) void*)g,
                                     (__attribute__((address_space(3))) void*)l,
                                     16, 0, 0);
}

// ============ K1: cayley (0..127) + perm-invert (128) + xcast_perm (129..1152) ============
__global__ __launch_bounds__(256) void k_prep(const float* __restrict__ Ro,
                                              const float* __restrict__ Ri,
                                              const int* __restrict__ perm_out,
                                              const float* __restrict__ x,
                                              const int* __restrict__ pii,
                                              float* __restrict__ Rout,
                                              u16* __restrict__ QT16,
                                              u16* __restrict__ P16,
                                              int* __restrict__ pinv_out,
                                              u16* __restrict__ xb) {
    const int b = blockIdx.x;
    const int t = threadIdx.x;
    if (b == 128) {
#pragma unroll
        for (int e = 0; e < 16; ++e) {
            int i = e * 256 + t;
            pinv_out[perm_out[i]] = i;
        }
        return;
    }
    if (b >= 129) {
        // ---------------- xcast + input permutation (8 rows/block) ----------------
        __shared__ __align__(16) float xr[4096];
        const int blk = b - 129;
        int pv[16];
#pragma unroll
        for (int q = 0; q < 4; ++q) *(i32x4*)&pv[q * 4] = *(const i32x4*)&pii[t * 16 + q * 4];
        for (int r = 0; r < 8; ++r) {
            size_t srow = (size_t)blk * 8 + r;
            const float* src = x + srow * 4096;
#pragma unroll
            for (int q = 0; q < 4; ++q)
                *(f32x4*)&xr[q * 1024 + t * 4] = *(const f32x4*)&src[q * 1024 + t * 4];
            __syncthreads();
            union { short8 v; u16 e[8]; } o0, o1;
#pragma unroll
            for (int j = 0; j < 8; ++j) { o0.e[j] = f2bf(xr[pv[j]]); o1.e[j] = f2bf(xr[pv[8 + j]]); }
            *(short8*)&xb[srow * 4096 + t * 16] = o0.v;
            *(short8*)&xb[srow * 4096 + t * 16 + 8] = o1.v;
            __syncthreads();
        }
        return;
    }
    // ---------------- Cayley-Neumann, 4x4 register-blocked ----------------
    __shared__ __align__(16) float Qs[64 * 64];
    __shared__ __align__(16) float Ps[64 * 68];
    __shared__ __align__(16) float Ts[64 * 68];
    const float* vec = (b < 64) ? (Ro + (size_t)b * NTRI) : (Ri + (size_t)(b - 64) * NTRI);
    int tr = t >> 4, tc = t & 15;
#pragma unroll
    for (int e = 0; e < 16; ++e) {
        int el = e * 256 + t;
        int i = el >> 6, j = el & 63;
        float q = 0.f;
        if (i < j) q =  vec[i * 63 - (i * (i - 1)) / 2 + (j - i - 1)];
        if (i > j) q = -vec[j * 63 - (j * (j - 1)) / 2 + (i - j - 1)];
        Qs[el] = q;
    }
    __syncthreads();
    float a2[4][4], a3[4][4], a4[4][4];
#pragma unroll
    for (int i = 0; i < 4; ++i)
#pragma unroll
        for (int j = 0; j < 4; ++j) { a2[i][j] = 0.f; a3[i][j] = 0.f; a4[i][j] = 0.f; }
    for (int k = 0; k < 64; ++k) {
        f32x4 qa = *(const f32x4*)&Qs[k * 64 + tr * 4];
        f32x4 qb = *(const f32x4*)&Qs[k * 64 + tc * 4];
#pragma unroll
        for (int i = 0; i < 4; ++i)
#pragma unroll
            for (int j = 0; j < 4; ++j) a2[i][j] -= qa[i] * qb[j];
    }
#pragma unroll
    for (int i = 0; i < 4; ++i)
#pragma unroll
        for (int j = 0; j < 4; ++j) Ps[(tr * 4 + i) * 68 + tc * 4 + j] = a2[i][j];
    __syncthreads();
    for (int k = 0; k < 64; ++k) {
        f32x4 pa = *(const f32x4*)&Ps[k * 68 + tr * 4];
        f32x4 qb = *(const f32x4*)&Qs[k * 64 + tc * 4];
#pragma unroll
        for (int i = 0; i < 4; ++i)
#pragma unroll
            for (int j = 0; j < 4; ++j) a3[i][j] += pa[i] * qb[j];
    }
#pragma unroll
    for (int i = 0; i < 4; ++i)
#pragma unroll
        for (int j = 0; j < 4; ++j) Ts[(tc * 4 + j) * 68 + tr * 4 + i] = -a3[i][j];  // Ts[k][i]=Q3[k][i]
    __syncthreads();
    for (int k = 0; k < 64; ++k) {
        f32x4 ta = *(const f32x4*)&Ts[k * 68 + tr * 4];
        f32x4 qb = *(const f32x4*)&Qs[k * 64 + tc * 4];
#pragma unroll
        for (int i = 0; i < 4; ++i)
#pragma unroll
            for (int j = 0; j < 4; ++j) a4[i][j] -= ta[i] * qb[j];
    }
    if (b < 64) {
        float* dst = Rout + (size_t)b * 4096;
        u16* qt = QT16 + (size_t)b * 4096;
#pragma unroll
        for (int i = 0; i < 4; ++i) {
            int gi = tr * 4 + i;
            f32x4 q4 = *(const f32x4*)&Qs[gi * 64 + tc * 4];
            f32x4 o;
#pragma unroll
            for (int j = 0; j < 4; ++j) {
                int gj = tc * 4 + j;
                o[j] = 2.f * (q4[j] + a2[i][j] + a3[i][j] + a4[i][j]) + ((gi == gj) ? 1.f : 0.f);
            }
            *(f32x4*)&dst[gi * 64 + tc * 4] = o;
#pragma unroll
            for (int j = 0; j < 4; ++j) qt[(tc * 4 + j) * 64 + gi] = f2bf(o[j]);  // QT[d][c]=R[c][d]
        }
    } else {
        u16* p = P16 + (size_t)(b - 64) * 4096;
#pragma unroll
        for (int i = 0; i < 4; ++i) {
            int gi = tr * 4 + i;
            f32x4 q4 = *(const f32x4*)&Qs[gi * 64 + tc * 4];
            u16x4 pk;
#pragma unroll
            for (int j = 0; j < 4; ++j) {
                int gj = tc * 4 + j;
                float v = 2.f * (q4[j] + a2[i][j] + a3[i][j] + a4[i][j]) + ((gi == gj) ? 1.f : 0.f);
                pk[j] = f2bf(v);
            }
            *(u16x4*)&p[gi * 64 + tc * 4] = pk;
        }
    }
}

// ================= K2: fold (0..2047) + bias (2048..2063) =================
__global__ __launch_bounds__(256) void k_work(const float* __restrict__ W,
                                              const u16* __restrict__ P16,
                                              const u16* __restrict__ QT16,
                                              const int* __restrict__ pinv_out,
                                              const float* __restrict__ bias,
                                              const float* __restrict__ Rout,
                                              const int* __restrict__ perm_out,
                                              u16* __restrict__ Ctp,
                                              float* __restrict__ bfinal) {
    const int fb = blockIdx.x;
    const int t = threadIdx.x;
    if (fb < 2048) {
        // ---------------- fused MFMA fold ----------------
        __shared__ __align__(16) u16 Wst[128 * 64];   // swizzled bf16 W tile
        __shared__ __align__(16) u16 Ut[64 * 128];    // Ut[i][c] swizzled
        const int s = fb & 63;
        const int br = fb >> 6;
        const int lane = t & 63;
        const int w = t >> 6;
        const int fl = lane & 15;
        const int kg = lane >> 4;

        short8 bfP[4][2];
        const u16* Pbase = P16 + (size_t)s * 4096;
#pragma unroll
        for (int nf = 0; nf < 4; ++nf)
#pragma unroll
            for (int kk = 0; kk < 2; ++kk)
                bfP[nf][kk] = *(const short8*)(Pbase + (nf * 16 + fl) * 64 + kk * 32 + kg * 8);

#pragma unroll
        for (int q = 0; q < 4; ++q) {
            int ci = q * 256 + t;
            int row = ci >> 3, slot = ci & 7;
            const float* src = W + (size_t)(br * 128 + row) * IN_F + s * 64 + slot * 8;
            f32x4 v0 = *(const f32x4*)src;
            f32x4 v1 = *(const f32x4*)(src + 4);
            union { short8 v; u16 e[8]; } cv;
            cv.e[0] = f2bf(v0[0]); cv.e[1] = f2bf(v0[1]); cv.e[2] = f2bf(v0[2]); cv.e[3] = f2bf(v0[3]);
            cv.e[4] = f2bf(v1[0]); cv.e[5] = f2bf(v1[1]); cv.e[6] = f2bf(v1[2]); cv.e[7] = f2bf(v1[3]);
            *(short8*)&Wst[row * 64 + (slot ^ (row & 7)) * 8] = cv.v;
        }
        __syncthreads();

        f32x4 acc1[2][4];
#pragma unroll
        for (int mf = 0; mf < 2; ++mf)
#pragma unroll
            for (int nf = 0; nf < 4; ++nf) acc1[mf][nf] = f32x4{0.f, 0.f, 0.f, 0.f};
#pragma unroll
        for (int mf = 0; mf < 2; ++mf) {
            int row = w * 32 + mf * 16 + fl;
#pragma unroll
            for (int kk = 0; kk < 2; ++kk) {
                short8 a = *(const short8*)&Wst[row * 64 + ((kk * 4 + kg) ^ (row & 7)) * 8];
#pragma unroll
                for (int nf = 0; nf < 4; ++nf)
                    acc1[mf][nf] = __builtin_amdgcn_mfma_f32_16x16x32_bf16(a, bfP[nf][kk], acc1[mf][nf], 0, 0, 0);
            }
        }
#pragma unroll
        for (int mf = 0; mf < 2; ++mf)
#pragma unroll
            for (int nf = 0; nf < 4; ++nf) {
                int i = nf * 16 + fl;
                int c = w * 32 + mf * 16 + kg * 4;
                u16x4 pk;
#pragma unroll
                for (int reg = 0; reg < 4; ++reg) pk[reg] = f2bf(acc1[mf][nf][reg]);
                int slot = c >> 3, half = (c >> 2) & 1;
                *(u16x4*)&Ut[i * 128 + ((slot ^ (i & 7)) << 3) + (half << 2)] = pk;
            }
        __syncthreads();

        const int rbl = w >> 1;
        const int r_g = br * 2 + rbl;
        short8 aQ[2][2];
#pragma unroll
        for (int mf2 = 0; mf2 < 2; ++mf2) {
            int d = (w & 1) * 32 + mf2 * 16 + fl;
#pragma unroll
            for (int kk = 0; kk < 2; ++kk)
                aQ[mf2][kk] = *(const short8*)(QT16 + (size_t)r_g * 4096 + d * 64 + kk * 32 + kg * 8);
        }
        f32x4 acc2[2][4];
#pragma unroll
        for (int mf2 = 0; mf2 < 2; ++mf2)
#pragma unroll
            for (int nf = 0; nf < 4; ++nf) acc2[mf2][nf] = f32x4{0.f, 0.f, 0.f, 0.f};
#pragma unroll
        for (int kk = 0; kk < 2; ++kk)
#pragma unroll
            for (int nf = 0; nf < 4; ++nf) {
                int i = nf * 16 + fl;
                int slot = rbl * 8 + kk * 4 + kg;
                short8 bu = *(const short8*)&Ut[i * 128 + ((slot ^ (i & 7)) << 3)];
#pragma unroll
                for (int mf2 = 0; mf2 < 2; ++mf2)
                    acc2[mf2][nf] = __builtin_amdgcn_mfma_f32_16x16x32_bf16(aQ[mf2][kk], bu, acc2[mf2][nf], 0, 0, 0);
            }
#pragma unroll
        for (int mf2 = 0; mf2 < 2; ++mf2)
#pragma unroll
            for (int reg = 0; reg < 4; ++reg) {
                int o_g = br * 128 + w * 32 + mf2 * 16 + kg * 4 + reg;
                int j = pinv_out[o_g];
                u16* dst = Ctp + (size_t)j * IN_F + s * 64;
#pragma unroll
                for (int nf = 0; nf < 4; ++nf)
                    dst[nf * 16 + fl] = f2bf(acc2[mf2][nf][reg]);
            }
    } else {
        // ---------------- bias: bfinal[j] = (bias . R_out_bd)[perm_out[j]] ------------
        int j = (fb - 2048) * 256 + t;
        int o = perm_out[j];
        int r = o >> 6, d = o & 63;
        const float* Rb = Rout + (size_t)r * 4096;
        const float* bb = bias + r * 64;
        float s = 0.f;
        for (int c = 0; c < 64; ++c) s += bb[c] * Rb[c * 64 + d];
        bfinal[j] = s;
    }
}

// ================= K3: GEMM — round-2 structure (best measured) =================
// 256x256 tile, BK=32, 8 waves (2Mx4N), 4 LDS buffers (128 KiB), 3-tile-deep
// counted-vmcnt prefetch, XOR-swizzled LDS (pre-swizzled global source), setprio.
__global__ __launch_bounds__(512, 2) void k_gemm(const u16* __restrict__ A,   // [8192][4096]
                                                 const u16* __restrict__ Bt,  // [4096][4096] N-major
                                                 const float* __restrict__ bias,
                                                 float* __restrict__ out) {
    __shared__ __align__(16) u16 lds[65536];   // 128 KiB: buf b at b*16384 (A:8192, B:8192 u16)
    const int t = threadIdx.x;
    const int lane = t & 63;
    const int wid = t >> 6;
    const int wr = wid >> 2, wc = wid & 3;

    int flat = blockIdx.y * gridDim.x + blockIdx.x;  // 0..511
    int swz  = (flat & 7) * 64 + (flat >> 3);        // XCD-contiguous work chunks
    int bm = swz >> 4;                               // 0..31
    int bn = swz & 15;                               // 0..15

    const int srow = t >> 2;                          // 0..127
    const int sks  = (t & 3) ^ ((t >> 3) & 3);
    const u16* sA0 = A  + (size_t)(bm * 256 + srow) * IN_F + sks * 8;
    const u16* sA1 = sA0 + (size_t)128 * IN_F;
    const u16* sB0 = Bt + (size_t)(bn * 256 + srow) * IN_F + sks * 8;
    const u16* sB1 = sB0 + (size_t)128 * IN_F;
    u16* dA = lds + t * 8;            // + buf*16384 (A region)
    u16* dB = lds + 8192 + t * 8;     // + buf*16384 (B region)

    const int frow = lane & 15;
    const int kg = lane >> 4;
    const int swzr = kg ^ ((frow >> 1) & 3);
    const int aoff = (wr * 128 + frow) * 32 + swzr * 8;           // u16 units
    const int boff = 8192 + (wc * 64 + frow) * 32 + swzr * 8;

    f32x4 acc[8][4];
#pragma unroll
    for (int m = 0; m < 8; ++m)
#pragma unroll
        for (int n = 0; n < 4; ++n) acc[m][n] = f32x4{0.f, 0.f, 0.f, 0.f};

    // prologue: stage tiles 0,1,2 (12 loads in flight)
#pragma unroll
    for (int p = 0; p < 3; ++p) {
        int off = p * 32;
        int bb = p * 16384;
        gload16(sA0 + off, dA + bb); gload16(sA1 + off, dA + bb + 4096);
        gload16(sB0 + off, dB + bb); gload16(sB1 + off, dB + bb + 4096);
    }
    asm volatile("s_waitcnt vmcnt(8)" ::: "memory");   // tile 0 landed
    __builtin_amdgcn_s_barrier();

    for (int t4 = 0; t4 < 128; t4 += 4) {
#pragma unroll
        for (int u = 0; u < 4; ++u) {
            const int kt = t4 + u;
            const u16* base = lds + u * 16384;
            short8 af[8], bf[4];
            const u16* pa = base + aoff;
            const u16* pb = base + boff;
#pragma unroll
            for (int m = 0; m < 8; ++m) af[m] = *(const short8*)(pa + m * 512);
#pragma unroll
            for (int n = 0; n < 4; ++n) bf[n] = *(const short8*)(pb + n * 512);
            // prefetch tile kt+3 into buf (kt+3)&3 (that buf's reads finished last iter)
            {
                int ts = kt + 3;
                int tsc = ts < 128 ? ts : 124;       // tail: dummy (never-read) loads keep vmcnt uniform
                int off = tsc * 32;
                int bb = ((kt + 3) & 3) * 16384;
                gload16(sA0 + off, dA + bb); gload16(sA1 + off, dA + bb + 4096);
                gload16(sB0 + off, dB + bb); gload16(sB1 + off, dB + bb + 4096);
            }
            __builtin_amdgcn_s_setprio(1);
#pragma unroll
            for (int m = 0; m < 8; ++m)
#pragma unroll
                for (int n = 0; n < 4; ++n)
                    acc[m][n] = __builtin_amdgcn_mfma_f32_16x16x32_bf16(af[m], bf[n], acc[m][n], 0, 0, 0);
            __builtin_amdgcn_s_setprio(0);
            asm volatile("s_waitcnt vmcnt(8)" ::: "memory");  // tile kt+1 landed; 8 stay in flight
            __builtin_amdgcn_s_barrier();
        }
    }
    asm volatile("s_waitcnt vmcnt(0)" ::: "memory");   // drain dummies before LDS dealloc

    const int col0 = bn * 256 + wc * 64 + frow;
    const int row0 = bm * 256 + wr * 128 + kg * 4;
    float bv[4];
#pragma unroll
    for (int n = 0; n < 4; ++n) bv[n] = bias[col0 + n * 16];
#pragma unroll
    for (int m = 0; m < 8; ++m)
#pragma unroll
        for (int n = 0; n < 4; ++n)
#pragma unroll
            for (int i = 0; i < 4; ++i)
                out[(size_t)(row0 + m * 16 + i) * OUT_F + col0 + n * 16] = acc[m][n][i] + bv[n];
}

extern "C" void kernel_launch(void* const* d_in, const int* in_sizes, int n_in,
                              void* d_out, int out_size, void* d_ws, size_t ws_size,
                              hipStream_t stream) {
    (void)in_sizes; (void)n_in; (void)out_size; (void)ws_size;
    const float* x    = (const float*)d_in[0];
    const float* Ro   = (const float*)d_in[1];
    const float* Ri   = (const float*)d_in[2];
    const float* W    = (const float*)d_in[3];
    const float* bias = (const float*)d_in[4];
    const int* perm_in_inv = (const int*)d_in[5];
    const int* perm_out    = (const int*)d_in[6];
    float* out = (float*)d_out;

    char* ws = (char*)d_ws;
    float* Rout   = (float*)(ws);                               // 1 MiB
    u16*   P16    = (u16*)(ws + (1ull << 20));                  // 512 KiB
    u16*   QT16   = (u16*)(ws + (1ull << 20) + (1 << 19));      // 512 KiB
    int*   pinvo  = (int*)(ws + (2ull << 20));                  // 16 KiB
    float* bfinal = (float*)(ws + (2ull << 20) + (1 << 16));    // 16 KiB
    u16*   Ctp    = (u16*)(ws + (4ull << 20));                  // 32 MiB
    u16*   xb     = (u16*)(ws + (36ull << 20));                 // 64 MiB

    k_prep<<<1153, 256, 0, stream>>>(Ro, Ri, perm_out, x, perm_in_inv,
                                     Rout, QT16, P16, pinvo, xb);
    k_work<<<2064, 256, 0, stream>>>(W, P16, QT16, pinvo, bias, Rout,
                                     perm_out, Ctp, bfinal);
    k_gemm<<<dim3(16, 32), 512, 0, stream>>>(xb, Ctp, bfinal, out);
}

// Round 9
// 312.967 us; speedup vs baseline: 1.0182x; 1.0182x over previous
//
#include <hip/hip_runtime.h>
#include <stdint.h>

#define IN_F 4096
#define OUT_F 4096
#define NTRI 2016

typedef unsigned short u16;
typedef __attribute__((ext_vector_type(8))) short short8;
typedef __attribute__((ext_vector_type(4))) float f32x4;
typedef __attribute__((ext_vector_type(4))) int i32x4;
typedef __attribute__((ext_vector_type(4))) unsigned short u16x4;

__device__ __forceinline__ u16 f2bf(float f) {
    uint32_t u = __builtin_bit_cast(uint32_t, f);
    u = (u + 0x7FFFu + ((u >> 16) & 1u)) >> 16;   // round-to-nearest-even
    return (u16)u;
}

__device__ __forceinline__ void gload16(const void* g, void* l) {
    __builtin_amdgcn_global_load_lds((__attribute__((address_space(1))) void*)g,
                                     (__attribute__((address_space(3))) void*)l,
                                     16, 0, 0);
}

// ============ K1: cayley (0..127) + perm-invert (128) + xcast_perm (129..1152) ============
__global__ __launch_bounds__(256) void k_prep(const float* __restrict__ Ro,
                                              const float* __restrict__ Ri,
                                              const int* __restrict__ perm_out,
                                              const float* __restrict__ x,
                                              const int* __restrict__ pii,
                                              float* __restrict__ Rout,
                                              u16* __restrict__ QT16,
                                              u16* __restrict__ P16,
                                              int* __restrict__ pinv_out,
                                              u16* __restrict__ xb) {
    const int b = blockIdx.x;
    const int t = threadIdx.x;
    if (b == 128) {
#pragma unroll
        for (int e = 0; e < 16; ++e) {
            int i = e * 256 + t;
            pinv_out[perm_out[i]] = i;
        }
        return;
    }
    if (b >= 129) {
        // ---------------- xcast + input permutation (8 rows/block) ----------------
        __shared__ __align__(16) float xr[4096];
        const int blk = b - 129;
        int pv[16];
#pragma unroll
        for (int q = 0; q < 4; ++q) *(i32x4*)&pv[q * 4] = *(const i32x4*)&pii[t * 16 + q * 4];
        for (int r = 0; r < 8; ++r) {
            size_t srow = (size_t)blk * 8 + r;
            const float* src = x + srow * 4096;
#pragma unroll
            for (int q = 0; q < 4; ++q)
                *(f32x4*)&xr[q * 1024 + t * 4] = *(const f32x4*)&src[q * 1024 + t * 4];
            __syncthreads();
            union { short8 v; u16 e[8]; } o0, o1;
#pragma unroll
            for (int j = 0; j < 8; ++j) { o0.e[j] = f2bf(xr[pv[j]]); o1.e[j] = f2bf(xr[pv[8 + j]]); }
            *(short8*)&xb[srow * 4096 + t * 16] = o0.v;
            *(short8*)&xb[srow * 4096 + t * 16 + 8] = o1.v;
            __syncthreads();
        }
        return;
    }
    // ---------------- Cayley-Neumann, 4x4 register-blocked ----------------
    __shared__ __align__(16) float Qs[64 * 64];
    __shared__ __align__(16) float Ps[64 * 68];
    __shared__ __align__(16) float Ts[64 * 68];
    const float* vec = (b < 64) ? (Ro + (size_t)b * NTRI) : (Ri + (size_t)(b - 64) * NTRI);
    int tr = t >> 4, tc = t & 15;
#pragma unroll
    for (int e = 0; e < 16; ++e) {
        int el = e * 256 + t;
        int i = el >> 6, j = el & 63;
        float q = 0.f;
        if (i < j) q =  vec[i * 63 - (i * (i - 1)) / 2 + (j - i - 1)];
        if (i > j) q = -vec[j * 63 - (j * (j - 1)) / 2 + (i - j - 1)];
        Qs[el] = q;
    }
    __syncthreads();
    float a2[4][4], a3[4][4], a4[4][4];
#pragma unroll
    for (int i = 0; i < 4; ++i)
#pragma unroll
        for (int j = 0; j < 4; ++j) { a2[i][j] = 0.f; a3[i][j] = 0.f; a4[i][j] = 0.f; }
    for (int k = 0; k < 64; ++k) {
        f32x4 qa = *(const f32x4*)&Qs[k * 64 + tr * 4];
        f32x4 qb = *(const f32x4*)&Qs[k * 64 + tc * 4];
#pragma unroll
        for (int i = 0; i < 4; ++i)
#pragma unroll
            for (int j = 0; j < 4; ++j) a2[i][j] -= qa[i] * qb[j];
    }
#pragma unroll
    for (int i = 0; i < 4; ++i)
#pragma unroll
        for (int j = 0; j < 4; ++j) Ps[(tr * 4 + i) * 68 + tc * 4 + j] = a2[i][j];
    __syncthreads();
    for (int k = 0; k < 64; ++k) {
        f32x4 pa = *(const f32x4*)&Ps[k * 68 + tr * 4];
        f32x4 qb = *(const f32x4*)&Qs[k * 64 + tc * 4];
#pragma unroll
        for (int i = 0; i < 4; ++i)
#pragma unroll
            for (int j = 0; j < 4; ++j) a3[i][j] += pa[i] * qb[j];
    }
#pragma unroll
    for (int i = 0; i < 4; ++i)
#pragma unroll
        for (int j = 0; j < 4; ++j) Ts[(tc * 4 + j) * 68 + tr * 4 + i] = -a3[i][j];  // Ts[k][i]=Q3[k][i]
    __syncthreads();
    for (int k = 0; k < 64; ++k) {
        f32x4 ta = *(const f32x4*)&Ts[k * 68 + tr * 4];
        f32x4 qb = *(const f32x4*)&Qs[k * 64 + tc * 4];
#pragma unroll
        for (int i = 0; i < 4; ++i)
#pragma unroll
            for (int j = 0; j < 4; ++j) a4[i][j] -= ta[i] * qb[j];
    }
    if (b < 64) {
        float* dst = Rout + (size_t)b * 4096;
        u16* qt = QT16 + (size_t)b * 4096;
#pragma unroll
        for (int i = 0; i < 4; ++i) {
            int gi = tr * 4 + i;
            f32x4 q4 = *(const f32x4*)&Qs[gi * 64 + tc * 4];
            f32x4 o;
#pragma unroll
            for (int j = 0; j < 4; ++j) {
                int gj = tc * 4 + j;
                o[j] = 2.f * (q4[j] + a2[i][j] + a3[i][j] + a4[i][j]) + ((gi == gj) ? 1.f : 0.f);
            }
            *(f32x4*)&dst[gi * 64 + tc * 4] = o;
#pragma unroll
            for (int j = 0; j < 4; ++j) qt[(tc * 4 + j) * 64 + gi] = f2bf(o[j]);  // QT[d][c]=R[c][d]
        }
    } else {
        u16* p = P16 + (size_t)(b - 64) * 4096;
#pragma unroll
        for (int i = 0; i < 4; ++i) {
            int gi = tr * 4 + i;
            f32x4 q4 = *(const f32x4*)&Qs[gi * 64 + tc * 4];
            u16x4 pk;
#pragma unroll
            for (int j = 0; j < 4; ++j) {
                int gj = tc * 4 + j;
                float v = 2.f * (q4[j] + a2[i][j] + a3[i][j] + a4[i][j]) + ((gi == gj) ? 1.f : 0.f);
                pk[j] = f2bf(v);
            }
            *(u16x4*)&p[gi * 64 + tc * 4] = pk;
        }
    }
}

// ================= K2: fold (0..2047) + bias (2048..2063) =================
__global__ __launch_bounds__(256) void k_work(const float* __restrict__ W,
                                              const u16* __restrict__ P16,
                                              const u16* __restrict__ QT16,
                                              const int* __restrict__ pinv_out,
                                              const float* __restrict__ bias,
                                              const float* __restrict__ Rout,
                                              const int* __restrict__ perm_out,
                                              u16* __restrict__ Ctp,
                                              float* __restrict__ bfinal) {
    const int fb = blockIdx.x;
    const int t = threadIdx.x;
    if (fb < 2048) {
        // ---------------- fused MFMA fold ----------------
        __shared__ __align__(16) u16 Wst[128 * 64];   // swizzled bf16 W tile
        __shared__ __align__(16) u16 Ut[64 * 128];    // Ut[i][c] swizzled
        const int s = fb & 63;
        const int br = fb >> 6;
        const int lane = t & 63;
        const int w = t >> 6;
        const int fl = lane & 15;
        const int kg = lane >> 4;

        short8 bfP[4][2];
        const u16* Pbase = P16 + (size_t)s * 4096;
#pragma unroll
        for (int nf = 0; nf < 4; ++nf)
#pragma unroll
            for (int kk = 0; kk < 2; ++kk)
                bfP[nf][kk] = *(const short8*)(Pbase + (nf * 16 + fl) * 64 + kk * 32 + kg * 8);

#pragma unroll
        for (int q = 0; q < 4; ++q) {
            int ci = q * 256 + t;
            int row = ci >> 3, slot = ci & 7;
            const float* src = W + (size_t)(br * 128 + row) * IN_F + s * 64 + slot * 8;
            f32x4 v0 = *(const f32x4*)src;
            f32x4 v1 = *(const f32x4*)(src + 4);
            union { short8 v; u16 e[8]; } cv;
            cv.e[0] = f2bf(v0[0]); cv.e[1] = f2bf(v0[1]); cv.e[2] = f2bf(v0[2]); cv.e[3] = f2bf(v0[3]);
            cv.e[4] = f2bf(v1[0]); cv.e[5] = f2bf(v1[1]); cv.e[6] = f2bf(v1[2]); cv.e[7] = f2bf(v1[3]);
            *(short8*)&Wst[row * 64 + (slot ^ (row & 7)) * 8] = cv.v;
        }
        __syncthreads();

        f32x4 acc1[2][4];
#pragma unroll
        for (int mf = 0; mf < 2; ++mf)
#pragma unroll
            for (int nf = 0; nf < 4; ++nf) acc1[mf][nf] = f32x4{0.f, 0.f, 0.f, 0.f};
#pragma unroll
        for (int mf = 0; mf < 2; ++mf) {
            int row = w * 32 + mf * 16 + fl;
#pragma unroll
            for (int kk = 0; kk < 2; ++kk) {
                short8 a = *(const short8*)&Wst[row * 64 + ((kk * 4 + kg) ^ (row & 7)) * 8];
#pragma unroll
                for (int nf = 0; nf < 4; ++nf)
                    acc1[mf][nf] = __builtin_amdgcn_mfma_f32_16x16x32_bf16(a, bfP[nf][kk], acc1[mf][nf], 0, 0, 0);
            }
        }
#pragma unroll
        for (int mf = 0; mf < 2; ++mf)
#pragma unroll
            for (int nf = 0; nf < 4; ++nf) {
                int i = nf * 16 + fl;
                int c = w * 32 + mf * 16 + kg * 4;
                u16x4 pk;
#pragma unroll
                for (int reg = 0; reg < 4; ++reg) pk[reg] = f2bf(acc1[mf][nf][reg]);
                int slot = c >> 3, half = (c >> 2) & 1;
                *(u16x4*)&Ut[i * 128 + ((slot ^ (i & 7)) << 3) + (half << 2)] = pk;
            }
        __syncthreads();

        const int rbl = w >> 1;
        const int r_g = br * 2 + rbl;
        short8 aQ[2][2];
#pragma unroll
        for (int mf2 = 0; mf2 < 2; ++mf2) {
            int d = (w & 1) * 32 + mf2 * 16 + fl;
#pragma unroll
            for (int kk = 0; kk < 2; ++kk)
                aQ[mf2][kk] = *(const short8*)(QT16 + (size_t)r_g * 4096 + d * 64 + kk * 32 + kg * 8);
        }
        f32x4 acc2[2][4];
#pragma unroll
        for (int mf2 = 0; mf2 < 2; ++mf2)
#pragma unroll
            for (int nf = 0; nf < 4; ++nf) acc2[mf2][nf] = f32x4{0.f, 0.f, 0.f, 0.f};
#pragma unroll
        for (int kk = 0; kk < 2; ++kk)
#pragma unroll
            for (int nf = 0; nf < 4; ++nf) {
                int i = nf * 16 + fl;
                int slot = rbl * 8 + kk * 4 + kg;
                short8 bu = *(const short8*)&Ut[i * 128 + ((slot ^ (i & 7)) << 3)];
#pragma unroll
                for (int mf2 = 0; mf2 < 2; ++mf2)
                    acc2[mf2][nf] = __builtin_amdgcn_mfma_f32_16x16x32_bf16(aQ[mf2][kk], bu, acc2[mf2][nf], 0, 0, 0);
            }
#pragma unroll
        for (int mf2 = 0; mf2 < 2; ++mf2)
#pragma unroll
            for (int reg = 0; reg < 4; ++reg) {
                int o_g = br * 128 + w * 32 + mf2 * 16 + kg * 4 + reg;
                int j = pinv_out[o_g];
                u16* dst = Ctp + (size_t)j * IN_F + s * 64;
#pragma unroll
                for (int nf = 0; nf < 4; ++nf)
                    dst[nf * 16 + fl] = f2bf(acc2[mf2][nf][reg]);
            }
    } else {
        // ---------------- bias: bfinal[j] = (bias . R_out_bd)[perm_out[j]] ------------
        int j = (fb - 2048) * 256 + t;
        int o = perm_out[j];
        int r = o >> 6, d = o & 63;
        const float* Rb = Rout + (size_t)r * 4096;
        const float* bb = bias + r * 64;
        float s = 0.f;
        for (int c = 0; c < 64; ++c) s += bb[c] * Rb[c * 64 + d];
        bfinal[j] = s;
    }
}

// ================= K3: GEMM — round-2 ring + register fragment double-buffer =================
// 256x256 tile, BK=32, 8 waves (2Mx4N), 4-slot LDS ring (128 KiB), counted vmcnt(4)
// (slot i+2 confirmed at end of slot i), XOR-swizzled LDS, setprio.
// NEW: fragments for slot i+1 are ds_read during slot i's MFMA cluster (reg dbuf),
// overlapping the 1129-cyc LDS read burst with the 1242-cyc MFMA cluster.
__global__ __launch_bounds__(512, 2) void k_gemm(const u16* __restrict__ A,   // [8192][4096]
                                                 const u16* __restrict__ Bt,  // [4096][4096] N-major
                                                 const float* __restrict__ bias,
                                                 float* __restrict__ out) {
    __shared__ __align__(16) u16 lds[65536];   // 4 slots x 16384 u16 (A:8192 + B:8192)
    const int t = threadIdx.x;
    const int lane = t & 63;
    const int wid = t >> 6;
    const int wr = wid >> 2, wc = wid & 3;

    int flat = blockIdx.y * gridDim.x + blockIdx.x;  // 0..511
    int swz  = (flat & 7) * 64 + (flat >> 3);        // XCD-contiguous work chunks
    int bm = swz >> 4;                               // 0..31
    int bn = swz & 15;                               // 0..15

    const int srow = t >> 2;                          // 0..127
    const int sks  = (t & 3) ^ ((t >> 3) & 3);
    const u16* sA0 = A  + (size_t)(bm * 256 + srow) * IN_F + sks * 8;
    const u16* sA1 = sA0 + (size_t)128 * IN_F;
    const u16* sB0 = Bt + (size_t)(bn * 256 + srow) * IN_F + sks * 8;
    const u16* sB1 = sB0 + (size_t)128 * IN_F;
    u16* dA = lds + t * 8;            // + slot*16384 (A region)
    u16* dB = lds + 8192 + t * 8;     // + slot*16384 (B region)

    const int frow = lane & 15;
    const int kg = lane >> 4;
    const int swzr = kg ^ ((frow >> 1) & 3);
    const int aoff = (wr * 128 + frow) * 32 + swzr * 8;           // u16 units
    const int boff = 8192 + (wc * 64 + frow) * 32 + swzr * 8;

#define STAGE(slot, kt) do { int bb_ = (slot) * 16384, off_ = (kt) * 32; \
        gload16(sA0 + off_, dA + bb_); gload16(sA1 + off_, dA + bb_ + 4096); \
        gload16(sB0 + off_, dB + bb_); gload16(sB1 + off_, dB + bb_ + 4096); } while (0)

#define LOADFRAGS(AF, BF, buf) do { const u16* base_ = lds + (buf) * 16384; \
        _Pragma("unroll") for (int m_ = 0; m_ < 8; ++m_) AF[m_] = *(const short8*)(base_ + aoff + m_ * 512); \
        _Pragma("unroll") for (int n_ = 0; n_ < 4; ++n_) BF[n_] = *(const short8*)(base_ + boff + n_ * 512); } while (0)

#define MFMAS(AF, BF) do { __builtin_amdgcn_s_setprio(1); \
        _Pragma("unroll") for (int m_ = 0; m_ < 8; ++m_) \
        _Pragma("unroll") for (int n_ = 0; n_ < 4; ++n_) \
            acc[m_][n_] = __builtin_amdgcn_mfma_f32_16x16x32_bf16(AF[m_], BF[n_], acc[m_][n_], 0, 0, 0); \
        __builtin_amdgcn_s_setprio(0); } while (0)

    f32x4 acc[8][4];
#pragma unroll
    for (int m = 0; m < 8; ++m)
#pragma unroll
        for (int n = 0; n < 4; ++n) acc[m][n] = f32x4{0.f, 0.f, 0.f, 0.f};

    // prologue: stage slots 0,1,2 (12 loads); confirm slots 0,1 landed
    STAGE(0, 0); STAGE(1, 1); STAGE(2, 2);
    asm volatile("s_waitcnt vmcnt(4)" ::: "memory");
    __builtin_amdgcn_s_barrier();

    short8 afX[8], bfX[4], afY[8], bfY[4];
    LOADFRAGS(afX, bfX, 0);    // frags for slot 0

    for (int ii = 0; ii < 64; ++ii) {
        // ---- slot i0 = 2*ii: compute X, prefetch Y <- buf (i0+1)&3 ----
        {
            const int i = 2 * ii;
            LOADFRAGS(afY, bfY, (i + 1) & 3);
            int ts = i + 3; if (ts > 127) ts = 127;   // tail: idempotent re-stage
            STAGE((i + 3) & 3, ts);
            MFMAS(afX, bfX);
            asm volatile("s_waitcnt vmcnt(4)" ::: "memory");  // slot i+2 landed
            __builtin_amdgcn_s_barrier();
        }
        // ---- slot i1 = 2*ii+1: compute Y, prefetch X <- buf (i1+1)&3 ----
        {
            const int i = 2 * ii + 1;
            LOADFRAGS(afX, bfX, (i + 1) & 3);
            int ts = i + 3; if (ts > 127) ts = 127;
            STAGE((i + 3) & 3, ts);
            MFMAS(afY, bfY);
            asm volatile("s_waitcnt vmcnt(4)" ::: "memory");
            __builtin_amdgcn_s_barrier();
        }
    }
    asm volatile("s_waitcnt vmcnt(0)" ::: "memory");   // drain tail dummies

    const int col0 = bn * 256 + wc * 64 + frow;
    const int row0 = bm * 256 + wr * 128 + kg * 4;
    float bv[4];
#pragma unroll
    for (int n = 0; n < 4; ++n) bv[n] = bias[col0 + n * 16];
#pragma unroll
    for (int m = 0; m < 8; ++m)
#pragma unroll
        for (int n = 0; n < 4; ++n)
#pragma unroll
            for (int i = 0; i < 4; ++i)
                out[(size_t)(row0 + m * 16 + i) * OUT_F + col0 + n * 16] = acc[m][n][i] + bv[n];
#undef STAGE
#undef LOADFRAGS
#undef MFMAS
}

extern "C" void kernel_launch(void* const* d_in, const int* in_sizes, int n_in,
                              void* d_out, int out_size, void* d_ws, size_t ws_size,
                              hipStream_t stream) {
    (void)in_sizes; (void)n_in; (void)out_size; (void)ws_size;
    const float* x    = (const float*)d_in[0];
    const float* Ro   = (const float*)d_in[1];
    const float* Ri   = (const float*)d_in[2];
    const float* W    = (const float*)d_in[3];
    const float* bias = (const float*)d_in[4];
    const int* perm_in_inv = (const int*)d_in[5];
    const int* perm_out    = (const int*)d_in[6];
    float* out = (float*)d_out;

    char* ws = (char*)d_ws;
    float* Rout   = (float*)(ws);                               // 1 MiB
    u16*   P16    = (u16*)(ws + (1ull << 20));                  // 512 KiB
    u16*   QT16   = (u16*)(ws + (1ull << 20) + (1 << 19));      // 512 KiB
    int*   pinvo  = (int*)(ws + (2ull << 20));                  // 16 KiB
    float* bfinal = (float*)(ws + (2ull << 20) + (1 << 16));    // 16 KiB
    u16*   Ctp    = (u16*)(ws + (4ull << 20));                  // 32 MiB
    u16*   xb     = (u16*)(ws + (36ull << 20));                 // 64 MiB

    k_prep<<<1153, 256, 0, stream>>>(Ro, Ri, perm_out, x, perm_in_inv,
                                     Rout, QT16, P16, pinvo, xb);
    k_work<<<2064, 256, 0, stream>>>(W, P16, QT16, pinvo, bias, Rout,
                                     perm_out, Ctp, bfinal);
    k_gemm<<<dim3(16, 32), 512, 0, stream>>>(xb, Ctp, bfinal, out);
}